// Round 9
// baseline (383.382 us; speedup 1.0000x reference)
//
#include <hip/hip_runtime.h>

#define D 128
#define NN 100000

typedef __attribute__((ext_vector_type(8))) short short8;
typedef __attribute__((ext_vector_type(16))) float floatx16;
typedef __attribute__((ext_vector_type(2))) float floatx2;

__device__ inline unsigned short bf16_rne(float f) {
    unsigned int u = __float_as_uint(f);
    u += 0x7fff + ((u >> 16) & 1);
    return (unsigned short)(u >> 16);
}
__device__ inline unsigned char fp8_enc1(float f) {
    return (unsigned char)(__builtin_amdgcn_cvt_pk_fp8_f32(f, f, 0, false) & 0xff);
}

// ---------------------------------------------------------------------------
// Fused prep: [0,12500) cvt feat->bf16+fp8 | [12500,12756) build Wt | rest zero
// packed counts (100000 bytes = 6250 uint4).
// ---------------------------------------------------------------------------
__global__ __launch_bounds__(256) void prep_kernel(
    const float* __restrict__ feat, unsigned short* __restrict__ feat16,
    unsigned char* __restrict__ feat8,
    const float* __restrict__ Ws0, const float* __restrict__ Wn0,
    const float* __restrict__ Ws1, const float* __restrict__ Wn1,
    unsigned short* __restrict__ wt0, unsigned short* __restrict__ wt1,
    unsigned int* __restrict__ counts_w)
{
    int bid = blockIdx.x;
    if (bid < 12500) {
        int i = bid * 256 + threadIdx.x;                 // float4 index
        float4 v = *(const float4*)(feat + (size_t)i * 4);
        unsigned short u[4] = { bf16_rne(v.x), bf16_rne(v.y), bf16_rne(v.z), bf16_rne(v.w) };
        *(uint2*)(feat16 + (size_t)i * 4) = *(uint2*)u;
        int w = __builtin_amdgcn_cvt_pk_fp8_f32(v.x, v.y, 0, false);
        w = __builtin_amdgcn_cvt_pk_fp8_f32(v.z, v.w, w, true);
        ((unsigned int*)feat8)[i] = (unsigned int)w;
    } else if (bid < 12756) {
        int i = (bid - 12500) * 256 + threadIdx.x;       // 0..65535
        int layer = i >> 15;
        int r = i & 32767;
        int n = r >> 8;
        int k = r & 255;
        const float* Ws = layer ? Ws1 : Ws0;
        const float* Wn = layer ? Wn1 : Wn0;
        float v = (k < 128) ? Ws[(size_t)k * 128 + n] : Wn[(size_t)(k - 128) * 128 + n];
        unsigned short* wt = layer ? wt1 : wt0;
        wt[(size_t)n * 256 + k] = bf16_rne(v);
    } else {
        int i = (bid - 12756) * 256 + threadIdx.x;       // uint4 index
        if (i < (NN / 4 + 3) / 4) ((uint4*)counts_w)[i] = make_uint4(0u, 0u, 0u, 0u);
    }
}

// ---------------------------------------------------------------------------
// CSR build: packed-8bit hist (+rank) -> scan -> streaming fill
// counts_w[d>>2] byte (d&3) holds count of dst d. Rank from returned byte.
// ---------------------------------------------------------------------------
__global__ __launch_bounds__(256) void hist_rank_kernel(
    const int* __restrict__ dst, unsigned int* __restrict__ counts_w,
    int* __restrict__ rank, int E)
{
    int e = blockIdx.x * 256 + threadIdx.x;
    if (e >= E) return;
    int d = dst[e];
    unsigned int sh = (unsigned int)(d & 3) * 8u;
    unsigned int old = atomicAdd(&counts_w[d >> 2], 1u << sh);
    rank[e] = (int)((old >> sh) & 0xffu);
}

// 1024 elements per block; thread t owns 4 consecutive elements = 1 packed word
__global__ __launch_bounds__(256) void scan1_kernel(
    const unsigned int* __restrict__ counts_w, int* __restrict__ row_ptr,
    int* __restrict__ blockSums, int N)
{
    __shared__ int sd[256];
    int t = threadIdx.x;
    int base = blockIdx.x * 1024;
    int widx = (base >> 2) + t;
    unsigned int w = (widx < (N + 3) / 4) ? counts_w[widx] : 0u;
    int v[4]; int tot = 0;
#pragma unroll
    for (int i = 0; i < 4; i++) {
        v[i] = (int)((w >> (8 * i)) & 0xffu);
        tot += v[i];
    }
    sd[t] = tot; __syncthreads();
    for (int off = 1; off < 256; off <<= 1) {
        int x = (t >= off) ? sd[t - off] : 0;
        __syncthreads();
        sd[t] += x;
        __syncthreads();
    }
    int excl = sd[t] - tot;
    if (t == 255) blockSums[blockIdx.x] = sd[255];
    int run = excl;
#pragma unroll
    for (int i = 0; i < 4; i++) {
        int idx = base + t * 4 + i;
        if (idx < N) row_ptr[idx] = run;
        run += v[i];
    }
}

__global__ __launch_bounds__(256) void scan2_kernel(
    const int* __restrict__ blockSums, int* __restrict__ blockOffs, int nb)
{
    __shared__ int sd[256];
    int t = threadIdx.x;
    int val = (t < nb) ? blockSums[t] : 0;
    sd[t] = val; __syncthreads();
    for (int off = 1; off < 256; off <<= 1) {
        int x = (t >= off) ? sd[t - off] : 0;
        __syncthreads();
        sd[t] += x;
        __syncthreads();
    }
    if (t < nb) blockOffs[t] = sd[t] - val;
}

__global__ __launch_bounds__(256) void scan3_kernel(
    int* __restrict__ row_ptr, const int* __restrict__ blockOffs, int N, int E)
{
    int i = blockIdx.x * 256 + threadIdx.x;
    if (i < N) row_ptr[i] += blockOffs[i >> 10];
    if (i == N) row_ptr[N] = E;
}

__global__ __launch_bounds__(256) void fill_stream_kernel(
    const int* __restrict__ src, const int* __restrict__ dst,
    const int* __restrict__ row_ptr, const int* __restrict__ rank,
    int* __restrict__ col, int E)
{
    int e = blockIdx.x * 256 + threadIdx.x;
    if (e >= E) return;
    col[row_ptr[dst[e]] + rank[e]] = src[e];
}

// ---------------------------------------------------------------------------
// Gather (fp8 table): msg16[node] = bf16( inv_deg * sum_j fp8row(col[j]) ).
// 16 lanes x uint2 (8 fp8 = 8B) per 128B row; 4 nodes per wave; 4-deep unroll.
// ---------------------------------------------------------------------------
__global__ __launch_bounds__(256) void gather8_kernel(
    const unsigned char* __restrict__ h8, const int* __restrict__ row_ptr,
    const int* __restrict__ col, const int* __restrict__ in_deg,
    unsigned short* __restrict__ msg16, int N)
{
    const int wave = threadIdx.x >> 6;
    const int lane = threadIdx.x & 63;
    const int quad = lane >> 4;
    const int ln16 = lane & 15;
    const int node = (blockIdx.x * 4 + wave) * 4 + quad;
    if (node >= N) return;

    const size_t lo = (size_t)ln16 * 8;   // byte offset within 128B row
    int beg = row_ptr[node];
    int end = row_ptr[node + 1];

    float f[8] = {0.f,0.f,0.f,0.f,0.f,0.f,0.f,0.f};
    int j = beg;
    for (; j + 4 <= end; j += 4) {
        int c0 = col[j], c1 = col[j + 1], c2 = col[j + 2], c3 = col[j + 3];
        uint2 u0 = *(const uint2*)(h8 + (size_t)c0 * D + lo);
        uint2 u1 = *(const uint2*)(h8 + (size_t)c1 * D + lo);
        uint2 u2 = *(const uint2*)(h8 + (size_t)c2 * D + lo);
        uint2 u3 = *(const uint2*)(h8 + (size_t)c3 * D + lo);
#pragma unroll
        for (int q = 0; q < 4; q++) {
            uint2 u = q == 0 ? u0 : q == 1 ? u1 : q == 2 ? u2 : u3;
            floatx2 p0 = __builtin_amdgcn_cvt_pk_f32_fp8((int)u.x, false);
            floatx2 p1 = __builtin_amdgcn_cvt_pk_f32_fp8((int)u.x, true);
            floatx2 p2 = __builtin_amdgcn_cvt_pk_f32_fp8((int)u.y, false);
            floatx2 p3 = __builtin_amdgcn_cvt_pk_f32_fp8((int)u.y, true);
            f[0] += p0.x; f[1] += p0.y; f[2] += p1.x; f[3] += p1.y;
            f[4] += p2.x; f[5] += p2.y; f[6] += p3.x; f[7] += p3.y;
        }
    }
    for (; j < end; ++j) {
        uint2 u = *(const uint2*)(h8 + (size_t)col[j] * D + lo);
        floatx2 p0 = __builtin_amdgcn_cvt_pk_f32_fp8((int)u.x, false);
        floatx2 p1 = __builtin_amdgcn_cvt_pk_f32_fp8((int)u.x, true);
        floatx2 p2 = __builtin_amdgcn_cvt_pk_f32_fp8((int)u.y, false);
        floatx2 p3 = __builtin_amdgcn_cvt_pk_f32_fp8((int)u.y, true);
        f[0] += p0.x; f[1] += p0.y; f[2] += p1.x; f[3] += p1.y;
        f[4] += p2.x; f[5] += p2.y; f[6] += p3.x; f[7] += p3.y;
    }
    int dg = in_deg[node];
    float invd = 1.f / (float)(dg > 1 ? dg : 1);
    unsigned short us[8];
#pragma unroll
    for (int i = 0; i < 8; i++) us[i] = bf16_rne(f[i] * invd);
    *(uint4*)(msg16 + (size_t)node * D + ln16 * 8) = *(const uint4*)us;
}

// ---------------------------------------------------------------------------
// MFMA dual-GEMM 32x32x16_bf16, B staged in LDS (64KB, one barrier).
// Block = 256 thr = 4 waves; 128 rows/block, 32 rows/wave.
// C/D: col=lane&31, row=(reg&3)+8*(reg>>2)+4*(lane>>5).
// do_ln: writes Out16 (bf16, GEMM self input) AND Out8 (fp8, gather table).
// ---------------------------------------------------------------------------
__global__ __launch_bounds__(256) void mfma32_kernel(
    const unsigned short* __restrict__ A16, const unsigned short* __restrict__ Msg16,
    const unsigned short* __restrict__ Wt,   // [128 n][256 k] bf16
    const float* __restrict__ bias,
    const float* __restrict__ ln_g, const float* __restrict__ ln_b,
    unsigned short* __restrict__ Out16, unsigned char* __restrict__ Out8,
    float* __restrict__ Out32, int N, int do_ln)
{
    __shared__ unsigned short sB[32768];   // 64 KB

    const int tid  = threadIdx.x;
    const int wave = tid >> 6;
    const int lane = tid & 63;
    const int half = lane >> 5;
    const int n32  = lane & 31;
    const int wrow0 = blockIdx.x * 128 + wave * 32;

    // ---- stage Wt -> LDS (swizzled) ----
#pragma unroll
    for (int i = 0; i < 16; i++) {
        int idx = tid + i * 256;          // 0..4095 (16B chunks)
        int n = idx & 127;
        int c = idx >> 7;                 // 0..31, k = c*8..c*8+7
        uint4 w = *(const uint4*)(Wt + (size_t)n * 256 + c * 8);
        int hs = c >> 4, kc = (c >> 1) & 7, hf = c & 1;
        int ct = n >> 5, nn = n & 31;
        int chunk = (((ct * 2 + hs) * 8 + kc) * 2 + hf) * 32 + nn;
        *(uint4*)&sB[(size_t)chunk * 8] = w;
    }
    __syncthreads();

    const int arow = wrow0 + n32;
    const bool arv = arow < N;
    const size_t koff = (size_t)half * 8;

    floatx16 acc[4];
#pragma unroll
    for (int ct = 0; ct < 4; ct++)
#pragma unroll
        for (int r = 0; r < 16; r++) acc[ct][r] = 0.f;

#pragma unroll
    for (int hs = 0; hs < 2; hs++) {
        const unsigned short* Asrc = hs ? Msg16 : A16;
#pragma unroll
        for (int kc = 0; kc < 8; kc++) {
            short8 a;
            if (arv) a = *(const short8*)(Asrc + (size_t)arow * D + kc * 16 + koff);
            else     a = (short8){0,0,0,0,0,0,0,0};
#pragma unroll
            for (int ct = 0; ct < 4; ct++) {
                short8 b = *(const short8*)&sB[((size_t)((ct * 2 + hs) * 8 + kc) * 64 + lane) * 8];
                acc[ct] = __builtin_amdgcn_mfma_f32_32x32x16_bf16(a, b, acc[ct], 0, 0, 0);
            }
        }
    }

    // ---- Epilogue ----
    float bb[4];
#pragma unroll
    for (int ct = 0; ct < 4; ct++) bb[ct] = bias[ct * 32 + n32];

    float v[4][16];
#pragma unroll
    for (int ct = 0; ct < 4; ct++)
#pragma unroll
        for (int r = 0; r < 16; r++) v[ct][r] = acc[ct][r] + bb[ct];

    if (do_ln) {
        float gg[4], be[4];
#pragma unroll
        for (int ct = 0; ct < 4; ct++) {
            gg[ct] = ln_g[ct * 32 + n32];
            be[ct] = ln_b[ct * 32 + n32];
        }
        float s[16], s2[16];
#pragma unroll
        for (int r = 0; r < 16; r++) {
            s[r]  = v[0][r] + v[1][r] + v[2][r] + v[3][r];
            s2[r] = v[0][r]*v[0][r] + v[1][r]*v[1][r] + v[2][r]*v[2][r] + v[3][r]*v[3][r];
        }
#pragma unroll
        for (int off = 1; off < 32; off <<= 1) {
#pragma unroll
            for (int r = 0; r < 16; r++) {
                s[r]  += __shfl_xor(s[r],  off);
                s2[r] += __shfl_xor(s2[r], off);
            }
        }
#pragma unroll
        for (int r = 0; r < 16; r++) {
            float mean = s[r] * (1.f / 128.f);
            float var  = s2[r] * (1.f / 128.f) - mean * mean;
            float rstd = rsqrtf(var + 1e-5f);
            int row_g = wrow0 + (r & 3) + 8 * (r >> 2) + 4 * half;
            if (row_g < N) {
#pragma unroll
                for (int ct = 0; ct < 4; ct++) {
                    float t = (v[ct][r] - mean) * rstd * gg[ct] + be[ct];
                    t = t > 0.f ? t : 0.f;
                    Out16[(size_t)row_g * D + ct * 32 + n32] = bf16_rne(t);
                    Out8[(size_t)row_g * D + ct * 32 + n32] = fp8_enc1(t);
                }
            }
        }
    } else {
#pragma unroll
        for (int r = 0; r < 16; r++) {
            int row_g = wrow0 + (r & 3) + 8 * (r >> 2) + 4 * half;
            if (row_g < N) {
#pragma unroll
                for (int ct = 0; ct < 4; ct++)
                    Out32[(size_t)row_g * D + ct * 32 + n32] = v[ct][r];
            }
        }
    }
}

// ---------------------------------------------------------------------------
extern "C" void kernel_launch(void* const* d_in, const int* in_sizes, int n_in,
                              void* d_out, int out_size, void* d_ws, size_t ws_size,
                              hipStream_t stream)
{
    const float* feat = (const float*)d_in[0];
    const float* Ws0  = (const float*)d_in[1];
    const float* Wn0  = (const float*)d_in[2];
    const float* b0   = (const float*)d_in[3];
    const float* Ws1  = (const float*)d_in[4];
    const float* Wn1  = (const float*)d_in[5];
    const float* b1   = (const float*)d_in[6];
    const float* lng  = (const float*)d_in[7];
    const float* lnb  = (const float*)d_in[8];
    const int* esrc   = (const int*)d_in[9];
    const int* edst   = (const int*)d_in[10];
    const int* indeg  = (const int*)d_in[11];

    const int N = NN;
    const int E = in_sizes[9];

    float* out = (float*)d_out;

    // ws: feat16 | col | row_ptr | wt0 | wt1 | bsums | boffs | D-region
    //   D-region overlay: [counts_w(packed) + rank] (CSR build) then [h1_16]
    // d_out overlay (51.2MB, dead until final write):
    //   [0, 25.6M): msg0 | [25.6M, 38.4M): feat8 | [38.4M, 51.2M): h18
    // msg1 -> feat16 region (dead after layer 0).
    char* ws = (char*)d_ws;
    size_t o = 0;
    auto alloc = [&](size_t bytes) { char* p = ws + o; o += (bytes + 15) & ~(size_t)15; return p; };
    unsigned short* feat16 = (unsigned short*)alloc((size_t)N * D * 2);
    int* col     = (int*)alloc((size_t)E * 4);
    int* row_ptr = (int*)alloc((size_t)(N + 1) * 4);
    unsigned short* wt0 = (unsigned short*)alloc(128 * 256 * 2);
    unsigned short* wt1 = (unsigned short*)alloc(128 * 256 * 2);
    int* bsums = (int*)alloc(1024);
    int* boffs = (int*)alloc(1024);
    char* regD = alloc((size_t)N * D * 2 > ((size_t)N * 4 + (size_t)E * 4 + 32)
                       ? (size_t)N * D * 2 : ((size_t)N * 4 + (size_t)E * 4 + 32));
    unsigned int* counts_w = (unsigned int*)regD;                       // N bytes packed
    int* rank = (int*)(regD + (((size_t)N * 4 + 15) & ~(size_t)15));    // E ints
    unsigned short* h116 = (unsigned short*)regD;

    unsigned short* msg0  = (unsigned short*)d_out;
    unsigned char*  feat8 = (unsigned char*)d_out + (size_t)N * D * 2;
    unsigned char*  h18   = (unsigned char*)d_out + (size_t)N * D * 3;
    unsigned short* msg1  = feat16;
    (void)ws_size;

    const int edge_blocks = (E + 255) / 256;
    const int gemm_blocks = (N + 127) / 128;
    const int gather_blocks = (N + 15) / 16;
    const int nb = (N + 1023) / 1024;
    const int zero_words16 = (N / 4 + 3) / 4;                 // uint4s to zero
    const int zero_blocks = (zero_words16 + 255) / 256;

    // --- fused prep: cvt feat->bf16+fp8, build Wt, zero packed counts ---
    prep_kernel<<<12500 + 256 + zero_blocks, 256, 0, stream>>>(
        feat, feat16, feat8, Ws0, Wn0, Ws1, Wn1, wt0, wt1, counts_w);

    // --- CSR build ---
    hist_rank_kernel<<<edge_blocks, 256, 0, stream>>>(edst, counts_w, rank, E);
    scan1_kernel<<<nb, 256, 0, stream>>>(counts_w, row_ptr, bsums, N);
    scan2_kernel<<<1, 256, 0, stream>>>(bsums, boffs, nb);
    scan3_kernel<<<(N + 256) / 256, 256, 0, stream>>>(row_ptr, boffs, N, E);
    fill_stream_kernel<<<edge_blocks, 256, 0, stream>>>(esrc, edst, row_ptr, rank, col, E);

    // --- Layer 0 ---
    gather8_kernel<<<gather_blocks, 256, 0, stream>>>(feat8, row_ptr, col, indeg, msg0, N);
    mfma32_kernel<<<gemm_blocks, 256, 0, stream>>>(
        feat16, msg0, wt0, b0, lng, lnb, h116, h18, nullptr, N, 1);

    // --- Layer 1 ---
    gather8_kernel<<<gather_blocks, 256, 0, stream>>>(h18, row_ptr, col, indeg, msg1, N);
    mfma32_kernel<<<gemm_blocks, 256, 0, stream>>>(
        h116, msg1, wt1, b1, nullptr, nullptr, nullptr, nullptr, out, N, 0);
}

// Round 10
// 319.662 us; speedup vs baseline: 1.1993x; 1.1993x over previous
//
#include <hip/hip_runtime.h>

#define D 128
#define NN 100000
#define PB 391          // coarse buckets: dst >> 8, 100000/256 -> 391
#define EPB 4096        // edges per partition block

typedef __attribute__((ext_vector_type(8))) short short8;
typedef __attribute__((ext_vector_type(16))) float floatx16;
typedef __attribute__((ext_vector_type(2))) float floatx2;

__device__ inline unsigned short bf16_rne(float f) {
    unsigned int u = __float_as_uint(f);
    u += 0x7fff + ((u >> 16) & 1);
    return (unsigned short)(u >> 16);
}
__device__ inline unsigned char fp8_enc1(float f) {
    return (unsigned char)(__builtin_amdgcn_cvt_pk_fp8_f32(f, f, 0, false) & 0xff);
}

// ---------------------------------------------------------------------------
// Fused prep: [0,12500) cvt feat->bf16+fp8 | [12500,12756) build Wt
// ---------------------------------------------------------------------------
__global__ __launch_bounds__(256) void prep_kernel(
    const float* __restrict__ feat, unsigned short* __restrict__ feat16,
    unsigned char* __restrict__ feat8,
    const float* __restrict__ Ws0, const float* __restrict__ Wn0,
    const float* __restrict__ Ws1, const float* __restrict__ Wn1,
    unsigned short* __restrict__ wt0, unsigned short* __restrict__ wt1)
{
    int bid = blockIdx.x;
    if (bid < 12500) {
        int i = bid * 256 + threadIdx.x;                 // float4 index
        float4 v = *(const float4*)(feat + (size_t)i * 4);
        unsigned short u[4] = { bf16_rne(v.x), bf16_rne(v.y), bf16_rne(v.z), bf16_rne(v.w) };
        *(uint2*)(feat16 + (size_t)i * 4) = *(uint2*)u;
        int w = __builtin_amdgcn_cvt_pk_fp8_f32(v.x, v.y, 0, false);
        w = __builtin_amdgcn_cvt_pk_fp8_f32(v.z, v.w, w, true);
        ((unsigned int*)feat8)[i] = (unsigned int)w;
    } else {
        int i = (bid - 12500) * 256 + threadIdx.x;       // 0..65535
        int layer = i >> 15;
        int r = i & 32767;
        int n = r >> 8;
        int k = r & 255;
        const float* Ws = layer ? Ws1 : Ws0;
        const float* Wn = layer ? Wn1 : Wn0;
        float v = (k < 128) ? Ws[(size_t)k * 128 + n] : Wn[(size_t)(k - 128) * 128 + n];
        unsigned short* wt = layer ? wt1 : wt0;
        wt[(size_t)n * 256 + k] = bf16_rne(v);
    }
}

// ---------------------------------------------------------------------------
// Partitioned CSR build: all per-edge counting in LDS atomics.
// P1: coarse count + per-(block,bucket) reservation (global atomics: <=PB/blk)
// ---------------------------------------------------------------------------
__global__ __launch_bounds__(256) void part_count_kernel(
    const int* __restrict__ dst, unsigned int* __restrict__ bucketCnt,
    unsigned int* __restrict__ blockBase, int E)
{
    __shared__ unsigned int h[PB];
    const int t = threadIdx.x;
    const int b = blockIdx.x;
    for (int i = t; i < PB; i += 256) h[i] = 0;
    __syncthreads();
    const int base = b * EPB;
#pragma unroll
    for (int k = 0; k < EPB / 256; k++) {
        int e = base + k * 256 + t;
        if (e < E) atomicAdd(&h[(unsigned)dst[e] >> 8], 1u);
    }
    __syncthreads();
    for (int i = t; i < PB; i += 256) {
        unsigned int c = h[i];
        unsigned int o = 0;
        if (c) o = atomicAdd(&bucketCnt[i], c);
        blockBase[(size_t)b * PB + i] = o;
    }
}

// single block: exclusive scan of PB bucket counts -> bucketStart[PB+1]
__global__ __launch_bounds__(512) void part_scan_kernel(
    const unsigned int* __restrict__ bucketCnt, unsigned int* __restrict__ bucketStart,
    int E)
{
    __shared__ unsigned int sd[512];
    int t = threadIdx.x;
    unsigned int v = (t < PB) ? bucketCnt[t] : 0u;
    sd[t] = v; __syncthreads();
    for (int off = 1; off < 512; off <<= 1) {
        unsigned int x = (t >= off) ? sd[t - off] : 0u;
        __syncthreads();
        sd[t] += x;
        __syncthreads();
    }
    if (t < PB) bucketStart[t] = sd[t] - v;
    if (t == 0) bucketStart[PB] = (unsigned int)E;
}

// P2: scatter packed (src<<8 | dst&255) into bucket regions; ranks via LDS.
__global__ __launch_bounds__(256) void part_scatter_kernel(
    const int* __restrict__ src, const int* __restrict__ dst,
    const unsigned int* __restrict__ bucketStart,
    const unsigned int* __restrict__ blockBase,
    unsigned int* __restrict__ pairs, int E)
{
    __shared__ unsigned int h[PB];
    const int t = threadIdx.x;
    const int b = blockIdx.x;
    for (int i = t; i < PB; i += 256) h[i] = 0;
    __syncthreads();
    const int base = b * EPB;
#pragma unroll
    for (int k = 0; k < EPB / 256; k++) {
        int e = base + k * 256 + t;
        if (e < E) {
            unsigned int d = (unsigned int)dst[e];
            unsigned int bk = d >> 8;
            unsigned int lr = atomicAdd(&h[bk], 1u);
            unsigned int pos = bucketStart[bk] + blockBase[(size_t)b * PB + bk] + lr;
            pairs[pos] = ((unsigned int)src[e] << 8) | (d & 255u);
        }
    }
}

// P3: per-bucket fine CSR (256 dsts): LDS hist + scan -> row_ptr, cursor -> col.
__global__ __launch_bounds__(256) void part_fine_kernel(
    const unsigned int* __restrict__ pairs, const unsigned int* __restrict__ bucketStart,
    int* __restrict__ row_ptr, int* __restrict__ col, int N, int E)
{
    __shared__ unsigned int h[256], sc[256], pos[256];
    const int t = threadIdx.x;
    const int b = blockIdx.x;
    h[t] = 0;
    __syncthreads();
    const unsigned int ebeg = bucketStart[b];
    const unsigned int eend = bucketStart[b + 1];
    for (unsigned int i = ebeg + t; i < eend; i += 256)
        atomicAdd(&h[pairs[i] & 255u], 1u);
    __syncthreads();
    sc[t] = h[t]; __syncthreads();
    for (int off = 1; off < 256; off <<= 1) {
        unsigned int x = (t >= off) ? sc[t - off] : 0u;
        __syncthreads();
        sc[t] += x;
        __syncthreads();
    }
    unsigned int excl = sc[t] - h[t];
    int node = b * 256 + t;
    if (node < N) row_ptr[node] = (int)(ebeg + excl);
    pos[t] = ebeg + excl;
    if (b == 0 && t == 0) row_ptr[N] = E;
    __syncthreads();
    for (unsigned int i = ebeg + t; i < eend; i += 256) {
        unsigned int p = pairs[i];
        unsigned int w = atomicAdd(&pos[p & 255u], 1u);
        col[w] = (int)(p >> 8);
    }
}

// ---------------------------------------------------------------------------
// Gather (fp8 table): msg16[node] = bf16( inv_deg * sum_j fp8row(col[j]) ).
// 16 lanes x uint2 (8 fp8 = 8B) per 128B row; 4 nodes per wave; 4-deep unroll.
// ---------------------------------------------------------------------------
__global__ __launch_bounds__(256) void gather8_kernel(
    const unsigned char* __restrict__ h8, const int* __restrict__ row_ptr,
    const int* __restrict__ col, const int* __restrict__ in_deg,
    unsigned short* __restrict__ msg16, int N)
{
    const int wave = threadIdx.x >> 6;
    const int lane = threadIdx.x & 63;
    const int quad = lane >> 4;
    const int ln16 = lane & 15;
    const int node = (blockIdx.x * 4 + wave) * 4 + quad;
    if (node >= N) return;

    const size_t lo = (size_t)ln16 * 8;   // byte offset within 128B row
    int beg = row_ptr[node];
    int end = row_ptr[node + 1];

    float f[8] = {0.f,0.f,0.f,0.f,0.f,0.f,0.f,0.f};
    int j = beg;
    for (; j + 4 <= end; j += 4) {
        int c0 = col[j], c1 = col[j + 1], c2 = col[j + 2], c3 = col[j + 3];
        uint2 u0 = *(const uint2*)(h8 + (size_t)c0 * D + lo);
        uint2 u1 = *(const uint2*)(h8 + (size_t)c1 * D + lo);
        uint2 u2 = *(const uint2*)(h8 + (size_t)c2 * D + lo);
        uint2 u3 = *(const uint2*)(h8 + (size_t)c3 * D + lo);
#pragma unroll
        for (int q = 0; q < 4; q++) {
            uint2 u = q == 0 ? u0 : q == 1 ? u1 : q == 2 ? u2 : u3;
            floatx2 p0 = __builtin_amdgcn_cvt_pk_f32_fp8((int)u.x, false);
            floatx2 p1 = __builtin_amdgcn_cvt_pk_f32_fp8((int)u.x, true);
            floatx2 p2 = __builtin_amdgcn_cvt_pk_f32_fp8((int)u.y, false);
            floatx2 p3 = __builtin_amdgcn_cvt_pk_f32_fp8((int)u.y, true);
            f[0] += p0.x; f[1] += p0.y; f[2] += p1.x; f[3] += p1.y;
            f[4] += p2.x; f[5] += p2.y; f[6] += p3.x; f[7] += p3.y;
        }
    }
    for (; j < end; ++j) {
        uint2 u = *(const uint2*)(h8 + (size_t)col[j] * D + lo);
        floatx2 p0 = __builtin_amdgcn_cvt_pk_f32_fp8((int)u.x, false);
        floatx2 p1 = __builtin_amdgcn_cvt_pk_f32_fp8((int)u.x, true);
        floatx2 p2 = __builtin_amdgcn_cvt_pk_f32_fp8((int)u.y, false);
        floatx2 p3 = __builtin_amdgcn_cvt_pk_f32_fp8((int)u.y, true);
        f[0] += p0.x; f[1] += p0.y; f[2] += p1.x; f[3] += p1.y;
        f[4] += p2.x; f[5] += p2.y; f[6] += p3.x; f[7] += p3.y;
    }
    int dg = in_deg[node];
    float invd = 1.f / (float)(dg > 1 ? dg : 1);
    unsigned short us[8];
#pragma unroll
    for (int i = 0; i < 8; i++) us[i] = bf16_rne(f[i] * invd);
    *(uint4*)(msg16 + (size_t)node * D + ln16 * 8) = *(const uint4*)us;
}

// ---------------------------------------------------------------------------
// MFMA dual-GEMM 32x32x16_bf16, B staged in LDS (64KB, one barrier).
// Block = 256 thr = 4 waves; 128 rows/block, 32 rows/wave.
// C/D: col=lane&31, row=(reg&3)+8*(reg>>2)+4*(lane>>5).
// do_ln: writes Out16 (bf16, GEMM self input) AND Out8 (fp8, gather table).
// ---------------------------------------------------------------------------
__global__ __launch_bounds__(256) void mfma32_kernel(
    const unsigned short* __restrict__ A16, const unsigned short* __restrict__ Msg16,
    const unsigned short* __restrict__ Wt,   // [128 n][256 k] bf16
    const float* __restrict__ bias,
    const float* __restrict__ ln_g, const float* __restrict__ ln_b,
    unsigned short* __restrict__ Out16, unsigned char* __restrict__ Out8,
    float* __restrict__ Out32, int N, int do_ln)
{
    __shared__ unsigned short sB[32768];   // 64 KB

    const int tid  = threadIdx.x;
    const int wave = tid >> 6;
    const int lane = tid & 63;
    const int half = lane >> 5;
    const int n32  = lane & 31;
    const int wrow0 = blockIdx.x * 128 + wave * 32;

    // ---- stage Wt -> LDS (swizzled) ----
#pragma unroll
    for (int i = 0; i < 16; i++) {
        int idx = tid + i * 256;          // 0..4095 (16B chunks)
        int n = idx & 127;
        int c = idx >> 7;                 // 0..31, k = c*8..c*8+7
        uint4 w = *(const uint4*)(Wt + (size_t)n * 256 + c * 8);
        int hs = c >> 4, kc = (c >> 1) & 7, hf = c & 1;
        int ct = n >> 5, nn = n & 31;
        int chunk = (((ct * 2 + hs) * 8 + kc) * 2 + hf) * 32 + nn;
        *(uint4*)&sB[(size_t)chunk * 8] = w;
    }
    __syncthreads();

    const int arow = wrow0 + n32;
    const bool arv = arow < N;
    const size_t koff = (size_t)half * 8;

    floatx16 acc[4];
#pragma unroll
    for (int ct = 0; ct < 4; ct++)
#pragma unroll
        for (int r = 0; r < 16; r++) acc[ct][r] = 0.f;

#pragma unroll
    for (int hs = 0; hs < 2; hs++) {
        const unsigned short* Asrc = hs ? Msg16 : A16;
#pragma unroll
        for (int kc = 0; kc < 8; kc++) {
            short8 a;
            if (arv) a = *(const short8*)(Asrc + (size_t)arow * D + kc * 16 + koff);
            else     a = (short8){0,0,0,0,0,0,0,0};
#pragma unroll
            for (int ct = 0; ct < 4; ct++) {
                short8 b = *(const short8*)&sB[((size_t)((ct * 2 + hs) * 8 + kc) * 64 + lane) * 8];
                acc[ct] = __builtin_amdgcn_mfma_f32_32x32x16_bf16(a, b, acc[ct], 0, 0, 0);
            }
        }
    }

    // ---- Epilogue ----
    float bb[4];
#pragma unroll
    for (int ct = 0; ct < 4; ct++) bb[ct] = bias[ct * 32 + n32];

    float v[4][16];
#pragma unroll
    for (int ct = 0; ct < 4; ct++)
#pragma unroll
        for (int r = 0; r < 16; r++) v[ct][r] = acc[ct][r] + bb[ct];

    if (do_ln) {
        float gg[4], be[4];
#pragma unroll
        for (int ct = 0; ct < 4; ct++) {
            gg[ct] = ln_g[ct * 32 + n32];
            be[ct] = ln_b[ct * 32 + n32];
        }
        float s[16], s2[16];
#pragma unroll
        for (int r = 0; r < 16; r++) {
            s[r]  = v[0][r] + v[1][r] + v[2][r] + v[3][r];
            s2[r] = v[0][r]*v[0][r] + v[1][r]*v[1][r] + v[2][r]*v[2][r] + v[3][r]*v[3][r];
        }
#pragma unroll
        for (int off = 1; off < 32; off <<= 1) {
#pragma unroll
            for (int r = 0; r < 16; r++) {
                s[r]  += __shfl_xor(s[r],  off);
                s2[r] += __shfl_xor(s2[r], off);
            }
        }
#pragma unroll
        for (int r = 0; r < 16; r++) {
            float mean = s[r] * (1.f / 128.f);
            float var  = s2[r] * (1.f / 128.f) - mean * mean;
            float rstd = rsqrtf(var + 1e-5f);
            int row_g = wrow0 + (r & 3) + 8 * (r >> 2) + 4 * half;
            if (row_g < N) {
#pragma unroll
                for (int ct = 0; ct < 4; ct++) {
                    float t = (v[ct][r] - mean) * rstd * gg[ct] + be[ct];
                    t = t > 0.f ? t : 0.f;
                    Out16[(size_t)row_g * D + ct * 32 + n32] = bf16_rne(t);
                    Out8[(size_t)row_g * D + ct * 32 + n32] = fp8_enc1(t);
                }
            }
        }
    } else {
#pragma unroll
        for (int r = 0; r < 16; r++) {
            int row_g = wrow0 + (r & 3) + 8 * (r >> 2) + 4 * half;
            if (row_g < N) {
#pragma unroll
                for (int ct = 0; ct < 4; ct++)
                    Out32[(size_t)row_g * D + ct * 32 + n32] = v[ct][r];
            }
        }
    }
}

// ---------------------------------------------------------------------------
extern "C" void kernel_launch(void* const* d_in, const int* in_sizes, int n_in,
                              void* d_out, int out_size, void* d_ws, size_t ws_size,
                              hipStream_t stream)
{
    const float* feat = (const float*)d_in[0];
    const float* Ws0  = (const float*)d_in[1];
    const float* Wn0  = (const float*)d_in[2];
    const float* b0   = (const float*)d_in[3];
    const float* Ws1  = (const float*)d_in[4];
    const float* Wn1  = (const float*)d_in[5];
    const float* b1   = (const float*)d_in[6];
    const float* lng  = (const float*)d_in[7];
    const float* lnb  = (const float*)d_in[8];
    const int* esrc   = (const int*)d_in[9];
    const int* edst   = (const int*)d_in[10];
    const int* indeg  = (const int*)d_in[11];

    const int N = NN;
    const int E = in_sizes[9];

    float* out = (float*)d_out;

    // ws: feat16 | col | row_ptr | wt0 | wt1 | regD
    //   regD overlay (CSR build): bucketCnt | bucketStart | blockBase | pairs
    //   regD overlay (compute):   h1_16
    // d_out overlay (51.2MB, dead until final write):
    //   [0, 25.6M): msg0 | [25.6M, 38.4M): feat8 | [38.4M, 51.2M): h18
    // msg1 -> feat16 region (dead after layer 0).
    const int nblk = (E + EPB - 1) / EPB;
    char* ws = (char*)d_ws;
    size_t o = 0;
    auto alloc = [&](size_t bytes) { char* p = ws + o; o += (bytes + 15) & ~(size_t)15; return p; };
    unsigned short* feat16 = (unsigned short*)alloc((size_t)N * D * 2);
    int* col     = (int*)alloc((size_t)E * 4);
    int* row_ptr = (int*)alloc((size_t)(N + 1) * 4);
    unsigned short* wt0 = (unsigned short*)alloc(128 * 256 * 2);
    unsigned short* wt1 = (unsigned short*)alloc(128 * 256 * 2);
    size_t csr_bytes = (size_t)(512 + 512 + (size_t)nblk * PB + E) * 4 + 64;
    char* regD = alloc((size_t)N * D * 2 > csr_bytes ? (size_t)N * D * 2 : csr_bytes);
    unsigned int* bucketCnt   = (unsigned int*)regD;                  // 512 slots
    unsigned int* bucketStart = bucketCnt + 512;                      // 512 slots
    unsigned int* blockBase   = bucketStart + 512;                    // nblk*PB
    unsigned int* pairs       = blockBase + (size_t)nblk * PB;        // E
    unsigned short* h116 = (unsigned short*)regD;

    unsigned short* msg0  = (unsigned short*)d_out;
    unsigned char*  feat8 = (unsigned char*)d_out + (size_t)N * D * 2;
    unsigned char*  h18   = (unsigned char*)d_out + (size_t)N * D * 3;
    unsigned short* msg1  = feat16;
    (void)ws_size;

    const int gemm_blocks = (N + 127) / 128;
    const int gather_blocks = (N + 15) / 16;

    // --- fused prep: cvt feat->bf16+fp8, build Wt ---
    prep_kernel<<<12500 + 256, 256, 0, stream>>>(
        feat, feat16, feat8, Ws0, Wn0, Ws1, Wn1, wt0, wt1);

    // --- partitioned CSR build ---
    hipMemsetAsync(bucketCnt, 0, 512 * 4, stream);
    part_count_kernel<<<nblk, 256, 0, stream>>>(edst, bucketCnt, blockBase, E);
    part_scan_kernel<<<1, 512, 0, stream>>>(bucketCnt, bucketStart, E);
    part_scatter_kernel<<<nblk, 256, 0, stream>>>(esrc, edst, bucketStart, blockBase, pairs, E);
    part_fine_kernel<<<PB, 256, 0, stream>>>(pairs, bucketStart, row_ptr, col, N, E);

    // --- Layer 0 ---
    gather8_kernel<<<gather_blocks, 256, 0, stream>>>(feat8, row_ptr, col, indeg, msg0, N);
    mfma32_kernel<<<gemm_blocks, 256, 0, stream>>>(
        feat16, msg0, wt0, b0, lng, lnb, h116, h18, nullptr, N, 1);

    // --- Layer 1 ---
    gather8_kernel<<<gather_blocks, 256, 0, stream>>>(h18, row_ptr, col, indeg, msg1, N);
    mfma32_kernel<<<gemm_blocks, 256, 0, stream>>>(
        h116, msg1, wt1, b1, nullptr, nullptr, nullptr, nullptr, out, N, 0);
}

// Round 11
// 315.815 us; speedup vs baseline: 1.2139x; 1.0122x over previous
//
#include <hip/hip_runtime.h>

#define D 128
#define NN 100000
#define PB 391          // coarse buckets: dst >> 8
#define EPB 4096        // edges per partition block
#define PREP_BLKS 12756 // 12500 cvt + 256 wt

typedef __attribute__((ext_vector_type(8))) short short8;
typedef __attribute__((ext_vector_type(16))) float floatx16;
typedef __attribute__((ext_vector_type(2))) float floatx2;

__device__ inline unsigned short bf16_rne(float f) {
    unsigned int u = __float_as_uint(f);
    u += 0x7fff + ((u >> 16) & 1);
    return (unsigned short)(u >> 16);
}
__device__ inline unsigned char fp8_enc1(float f) {
    return (unsigned char)(__builtin_amdgcn_cvt_pk_fp8_f32(f, f, 0, false) & 0xff);
}

// ---------------------------------------------------------------------------
// Fused prep+count: [0,12500) cvt feat->bf16+fp8 | [12500,12756) build Wt |
// [12756, 12756+nblk) coarse edge count (bucketCnt must be pre-zeroed).
// ---------------------------------------------------------------------------
__global__ __launch_bounds__(256) void prep_count_kernel(
    const float* __restrict__ feat, unsigned short* __restrict__ feat16,
    unsigned char* __restrict__ feat8,
    const float* __restrict__ Ws0, const float* __restrict__ Wn0,
    const float* __restrict__ Ws1, const float* __restrict__ Wn1,
    unsigned short* __restrict__ wt0, unsigned short* __restrict__ wt1,
    const int* __restrict__ dst, unsigned int* __restrict__ bucketCnt,
    unsigned int* __restrict__ blockBase, int E)
{
    __shared__ unsigned int h[PB];
    int bid = blockIdx.x;
    if (bid < 12500) {
        int i = bid * 256 + threadIdx.x;                 // float4 index
        float4 v = *(const float4*)(feat + (size_t)i * 4);
        unsigned short u[4] = { bf16_rne(v.x), bf16_rne(v.y), bf16_rne(v.z), bf16_rne(v.w) };
        *(uint2*)(feat16 + (size_t)i * 4) = *(uint2*)u;
        int w = __builtin_amdgcn_cvt_pk_fp8_f32(v.x, v.y, 0, false);
        w = __builtin_amdgcn_cvt_pk_fp8_f32(v.z, v.w, w, true);
        ((unsigned int*)feat8)[i] = (unsigned int)w;
    } else if (bid < PREP_BLKS) {
        int i = (bid - 12500) * 256 + threadIdx.x;       // 0..65535
        int layer = i >> 15;
        int r = i & 32767;
        int n = r >> 8;
        int k = r & 255;
        const float* Ws = layer ? Ws1 : Ws0;
        const float* Wn = layer ? Wn1 : Wn0;
        float v = (k < 128) ? Ws[(size_t)k * 128 + n] : Wn[(size_t)(k - 128) * 128 + n];
        unsigned short* wt = layer ? wt1 : wt0;
        wt[(size_t)n * 256 + k] = bf16_rne(v);
    } else {
        const int b = bid - PREP_BLKS;
        const int t = threadIdx.x;
        for (int i = t; i < PB; i += 256) h[i] = 0;
        __syncthreads();
        const int base = b * EPB;
#pragma unroll
        for (int k = 0; k < EPB / 256; k++) {
            int e = base + k * 256 + t;
            if (e < E) atomicAdd(&h[(unsigned)dst[e] >> 8], 1u);
        }
        __syncthreads();
        for (int i = t; i < PB; i += 256) {
            unsigned int c = h[i];
            unsigned int o = 0;
            if (c) o = atomicAdd(&bucketCnt[i], c);
            blockBase[(size_t)b * PB + i] = o;
        }
    }
}

// single block: exclusive scan of PB bucket counts -> bucketStart[PB+1]
__global__ __launch_bounds__(512) void part_scan_kernel(
    const unsigned int* __restrict__ bucketCnt, unsigned int* __restrict__ bucketStart,
    int E)
{
    __shared__ unsigned int sd[512];
    int t = threadIdx.x;
    unsigned int v = (t < PB) ? bucketCnt[t] : 0u;
    sd[t] = v; __syncthreads();
    for (int off = 1; off < 512; off <<= 1) {
        unsigned int x = (t >= off) ? sd[t - off] : 0u;
        __syncthreads();
        sd[t] += x;
        __syncthreads();
    }
    if (t < PB) bucketStart[t] = sd[t] - v;
    if (t == 0) bucketStart[PB] = (unsigned int)E;
}

// P2: scatter packed (src<<8 | dst&255) into bucket regions; ranks via LDS.
__global__ __launch_bounds__(256) void part_scatter_kernel(
    const int* __restrict__ src, const int* __restrict__ dst,
    const unsigned int* __restrict__ bucketStart,
    const unsigned int* __restrict__ blockBase,
    unsigned int* __restrict__ pairs, int E)
{
    __shared__ unsigned int h[PB];
    const int t = threadIdx.x;
    const int b = blockIdx.x;
    for (int i = t; i < PB; i += 256) h[i] = 0;
    __syncthreads();
    const int base = b * EPB;
#pragma unroll
    for (int k = 0; k < EPB / 256; k++) {
        int e = base + k * 256 + t;
        if (e < E) {
            unsigned int d = (unsigned int)dst[e];
            unsigned int bk = d >> 8;
            unsigned int lr = atomicAdd(&h[bk], 1u);
            unsigned int pos = bucketStart[bk] + blockBase[(size_t)b * PB + bk] + lr;
            pairs[pos] = ((unsigned int)src[e] << 8) | (d & 255u);
        }
    }
}

// P3: per-bucket fine CSR (256 dsts): LDS hist + scan -> row_ptr, cursor -> col.
__global__ __launch_bounds__(256) void part_fine_kernel(
    const unsigned int* __restrict__ pairs, const unsigned int* __restrict__ bucketStart,
    int* __restrict__ row_ptr, int* __restrict__ col, int N, int E)
{
    __shared__ unsigned int h[256], sc[256], pos[256];
    const int t = threadIdx.x;
    const int b = blockIdx.x;
    h[t] = 0;
    __syncthreads();
    const unsigned int ebeg = bucketStart[b];
    const unsigned int eend = bucketStart[b + 1];
    for (unsigned int i = ebeg + t; i < eend; i += 256)
        atomicAdd(&h[pairs[i] & 255u], 1u);
    __syncthreads();
    sc[t] = h[t]; __syncthreads();
    for (int off = 1; off < 256; off <<= 1) {
        unsigned int x = (t >= off) ? sc[t - off] : 0u;
        __syncthreads();
        sc[t] += x;
        __syncthreads();
    }
    unsigned int excl = sc[t] - h[t];
    int node = b * 256 + t;
    if (node < N) row_ptr[node] = (int)(ebeg + excl);
    pos[t] = ebeg + excl;
    if (b == 0 && t == 0) row_ptr[N] = E;
    __syncthreads();
    for (unsigned int i = ebeg + t; i < eend; i += 256) {
        unsigned int p = pairs[i];
        unsigned int w = atomicAdd(&pos[p & 255u], 1u);
        col[w] = (int)(p >> 8);
    }
}

// ---------------------------------------------------------------------------
// Gather (fp8 table): msg16[node] = bf16( inv_deg * sum_j fp8row(col[j]) ).
// 16 lanes x uint2 (8 fp8 = 8B) per 128B row; 4 nodes per wave; 4-deep unroll.
// ---------------------------------------------------------------------------
__global__ __launch_bounds__(256) void gather8_kernel(
    const unsigned char* __restrict__ h8, const int* __restrict__ row_ptr,
    const int* __restrict__ col, const int* __restrict__ in_deg,
    unsigned short* __restrict__ msg16, int N)
{
    const int wave = threadIdx.x >> 6;
    const int lane = threadIdx.x & 63;
    const int quad = lane >> 4;
    const int ln16 = lane & 15;
    const int node = (blockIdx.x * 4 + wave) * 4 + quad;
    if (node >= N) return;

    const size_t lo = (size_t)ln16 * 8;   // byte offset within 128B row
    int beg = row_ptr[node];
    int end = row_ptr[node + 1];

    float f[8] = {0.f,0.f,0.f,0.f,0.f,0.f,0.f,0.f};
    int j = beg;
    for (; j + 4 <= end; j += 4) {
        int c0 = col[j], c1 = col[j + 1], c2 = col[j + 2], c3 = col[j + 3];
        uint2 u0 = *(const uint2*)(h8 + (size_t)c0 * D + lo);
        uint2 u1 = *(const uint2*)(h8 + (size_t)c1 * D + lo);
        uint2 u2 = *(const uint2*)(h8 + (size_t)c2 * D + lo);
        uint2 u3 = *(const uint2*)(h8 + (size_t)c3 * D + lo);
#pragma unroll
        for (int q = 0; q < 4; q++) {
            uint2 u = q == 0 ? u0 : q == 1 ? u1 : q == 2 ? u2 : u3;
            floatx2 p0 = __builtin_amdgcn_cvt_pk_f32_fp8((int)u.x, false);
            floatx2 p1 = __builtin_amdgcn_cvt_pk_f32_fp8((int)u.x, true);
            floatx2 p2 = __builtin_amdgcn_cvt_pk_f32_fp8((int)u.y, false);
            floatx2 p3 = __builtin_amdgcn_cvt_pk_f32_fp8((int)u.y, true);
            f[0] += p0.x; f[1] += p0.y; f[2] += p1.x; f[3] += p1.y;
            f[4] += p2.x; f[5] += p2.y; f[6] += p3.x; f[7] += p3.y;
        }
    }
    for (; j < end; ++j) {
        uint2 u = *(const uint2*)(h8 + (size_t)col[j] * D + lo);
        floatx2 p0 = __builtin_amdgcn_cvt_pk_f32_fp8((int)u.x, false);
        floatx2 p1 = __builtin_amdgcn_cvt_pk_f32_fp8((int)u.x, true);
        floatx2 p2 = __builtin_amdgcn_cvt_pk_f32_fp8((int)u.y, false);
        floatx2 p3 = __builtin_amdgcn_cvt_pk_f32_fp8((int)u.y, true);
        f[0] += p0.x; f[1] += p0.y; f[2] += p1.x; f[3] += p1.y;
        f[4] += p2.x; f[5] += p2.y; f[6] += p3.x; f[7] += p3.y;
    }
    int dg = in_deg[node];
    float invd = 1.f / (float)(dg > 1 ? dg : 1);
    unsigned short us[8];
#pragma unroll
    for (int i = 0; i < 8; i++) us[i] = bf16_rne(f[i] * invd);
    *(uint4*)(msg16 + (size_t)node * D + ln16 * 8) = *(const uint4*)us;
}

// ---------------------------------------------------------------------------
// MFMA dual-GEMM 32x32x16_bf16, B staged in LDS; coalesced epilogue via LDS
// transpose (sB reused after K-loop). Block = 256 thr = 4 waves; 128 rows.
// C/D: col=lane&31, row=(reg&3)+8*(reg>>2)+4*(lane>>5).
// ---------------------------------------------------------------------------
__global__ __launch_bounds__(256) void mfma32_kernel(
    const unsigned short* __restrict__ A16, const unsigned short* __restrict__ Msg16,
    const unsigned short* __restrict__ Wt,   // [128 n][256 k] bf16
    const float* __restrict__ bias,
    const float* __restrict__ ln_g, const float* __restrict__ ln_b,
    unsigned short* __restrict__ Out16, unsigned char* __restrict__ Out8,
    float* __restrict__ Out32, int N, int do_ln)
{
    __shared__ unsigned short sB[32768];   // 64 KB (reused by epilogue)

    const int tid  = threadIdx.x;
    const int wave = tid >> 6;
    const int lane = tid & 63;
    const int half = lane >> 5;
    const int n32  = lane & 31;
    const int brow0 = blockIdx.x * 128;
    const int wrow0 = brow0 + wave * 32;

    // ---- stage Wt -> LDS (swizzled) ----
#pragma unroll
    for (int i = 0; i < 16; i++) {
        int idx = tid + i * 256;          // 0..4095 (16B chunks)
        int n = idx & 127;
        int c = idx >> 7;                 // 0..31, k = c*8..c*8+7
        uint4 w = *(const uint4*)(Wt + (size_t)n * 256 + c * 8);
        int hs = c >> 4, kc = (c >> 1) & 7, hf = c & 1;
        int ct = n >> 5, nn = n & 31;
        int chunk = (((ct * 2 + hs) * 8 + kc) * 2 + hf) * 32 + nn;
        *(uint4*)&sB[(size_t)chunk * 8] = w;
    }
    __syncthreads();

    const int arow = wrow0 + n32;
    const bool arv = arow < N;
    const size_t koff = (size_t)half * 8;

    floatx16 acc[4];
#pragma unroll
    for (int ct = 0; ct < 4; ct++)
#pragma unroll
        for (int r = 0; r < 16; r++) acc[ct][r] = 0.f;

#pragma unroll
    for (int hs = 0; hs < 2; hs++) {
        const unsigned short* Asrc = hs ? Msg16 : A16;
#pragma unroll
        for (int kc = 0; kc < 8; kc++) {
            short8 a;
            if (arv) a = *(const short8*)(Asrc + (size_t)arow * D + kc * 16 + koff);
            else     a = (short8){0,0,0,0,0,0,0,0};
#pragma unroll
            for (int ct = 0; ct < 4; ct++) {
                short8 b = *(const short8*)&sB[((size_t)((ct * 2 + hs) * 8 + kc) * 64 + lane) * 8];
                acc[ct] = __builtin_amdgcn_mfma_f32_32x32x16_bf16(a, b, acc[ct], 0, 0, 0);
            }
        }
    }

    // ---- Epilogue ----
    float bb[4];
#pragma unroll
    for (int ct = 0; ct < 4; ct++) bb[ct] = bias[ct * 32 + n32];

    float v[4][16];
#pragma unroll
    for (int ct = 0; ct < 4; ct++)
#pragma unroll
        for (int r = 0; r < 16; r++) v[ct][r] = acc[ct][r] + bb[ct];

    __syncthreads();   // sB (B-fragments) dead; reuse as output staging

    if (do_ln) {
        float gg[4], be[4];
#pragma unroll
        for (int ct = 0; ct < 4; ct++) {
            gg[ct] = ln_g[ct * 32 + n32];
            be[ct] = ln_b[ct * 32 + n32];
        }
        float s[16], s2[16];
#pragma unroll
        for (int r = 0; r < 16; r++) {
            s[r]  = v[0][r] + v[1][r] + v[2][r] + v[3][r];
            s2[r] = v[0][r]*v[0][r] + v[1][r]*v[1][r] + v[2][r]*v[2][r] + v[3][r]*v[3][r];
        }
#pragma unroll
        for (int off = 1; off < 32; off <<= 1) {
#pragma unroll
            for (int r = 0; r < 16; r++) {
                s[r]  += __shfl_xor(s[r],  off);
                s2[r] += __shfl_xor(s2[r], off);
            }
        }
        unsigned short* sO16 = sB;                               // [128][128] ushort
        unsigned char*  sO8  = (unsigned char*)sB + 32768;       // [128][128] byte
#pragma unroll
        for (int r = 0; r < 16; r++) {
            float mean = s[r] * (1.f / 128.f);
            float var  = s2[r] * (1.f / 128.f) - mean * mean;
            float rstd = rsqrtf(var + 1e-5f);
            int brow = wave * 32 + (r & 3) + 8 * (r >> 2) + 4 * half;
#pragma unroll
            for (int ct = 0; ct < 4; ct++) {
                float t = (v[ct][r] - mean) * rstd * gg[ct] + be[ct];
                t = t > 0.f ? t : 0.f;
                sO16[brow * 128 + ct * 32 + n32] = bf16_rne(t);
                sO8 [brow * 128 + ct * 32 + n32] = fp8_enc1(t);
            }
        }
        __syncthreads();
        // linear copy LDS -> global (1KB/wave-instruction)
#pragma unroll
        for (int i = 0; i < 8; i++) {                 // bf16: 2048 uint4 chunks
            int ch = tid + i * 256;
            if (brow0 + (ch >> 4) < N)
                *(uint4*)(Out16 + (size_t)brow0 * D + ch * 8) = *(const uint4*)&sO16[ch * 8];
        }
#pragma unroll
        for (int i = 0; i < 4; i++) {                 // fp8: 1024 uint4 chunks
            int ch = tid + i * 256;
            if (brow0 + (ch >> 3) < N)
                *(uint4*)(Out8 + (size_t)brow0 * D + ch * 16) = *(const uint4*)&sO8[ch * 16];
        }
    } else {
        float* sO32 = (float*)sB;                                // [128][128] float
#pragma unroll
        for (int r = 0; r < 16; r++) {
            int brow = wave * 32 + (r & 3) + 8 * (r >> 2) + 4 * half;
#pragma unroll
            for (int ct = 0; ct < 4; ct++)
                sO32[brow * 128 + ct * 32 + n32] = v[ct][r];
        }
        __syncthreads();
#pragma unroll
        for (int i = 0; i < 16; i++) {                // fp32: 4096 uint4 chunks
            int ch = tid + i * 256;
            if (brow0 + (ch >> 5) < N)
                *(uint4*)(Out32 + (size_t)brow0 * D + ch * 4) = *(const uint4*)&sO32[ch * 4];
        }
    }
}

// ---------------------------------------------------------------------------
extern "C" void kernel_launch(void* const* d_in, const int* in_sizes, int n_in,
                              void* d_out, int out_size, void* d_ws, size_t ws_size,
                              hipStream_t stream)
{
    const float* feat = (const float*)d_in[0];
    const float* Ws0  = (const float*)d_in[1];
    const float* Wn0  = (const float*)d_in[2];
    const float* b0   = (const float*)d_in[3];
    const float* Ws1  = (const float*)d_in[4];
    const float* Wn1  = (const float*)d_in[5];
    const float* b1   = (const float*)d_in[6];
    const float* lng  = (const float*)d_in[7];
    const float* lnb  = (const float*)d_in[8];
    const int* esrc   = (const int*)d_in[9];
    const int* edst   = (const int*)d_in[10];
    const int* indeg  = (const int*)d_in[11];

    const int N = NN;
    const int E = in_sizes[9];

    float* out = (float*)d_out;

    // ws: feat16 | col | row_ptr | wt0 | wt1 | regD
    //   regD overlay (CSR build): bucketCnt | bucketStart | blockBase | pairs
    //   regD overlay (compute):   h1_16
    // d_out overlay (51.2MB, dead until final write):
    //   [0, 25.6M): msg0 | [25.6M, 38.4M): feat8 | [38.4M, 51.2M): h18
    // msg1 -> feat16 region (dead after layer 0).
    const int nblk = (E + EPB - 1) / EPB;
    char* ws = (char*)d_ws;
    size_t o = 0;
    auto alloc = [&](size_t bytes) { char* p = ws + o; o += (bytes + 15) & ~(size_t)15; return p; };
    unsigned short* feat16 = (unsigned short*)alloc((size_t)N * D * 2);
    int* col     = (int*)alloc((size_t)E * 4);
    int* row_ptr = (int*)alloc((size_t)(N + 1) * 4);
    unsigned short* wt0 = (unsigned short*)alloc(128 * 256 * 2);
    unsigned short* wt1 = (unsigned short*)alloc(128 * 256 * 2);
    size_t csr_bytes = (size_t)(512 + 512 + (size_t)nblk * PB + E) * 4 + 64;
    char* regD = alloc((size_t)N * D * 2 > csr_bytes ? (size_t)N * D * 2 : csr_bytes);
    unsigned int* bucketCnt   = (unsigned int*)regD;                  // 512 slots
    unsigned int* bucketStart = bucketCnt + 512;                      // 512 slots
    unsigned int* blockBase   = bucketStart + 512;                    // nblk*PB
    unsigned int* pairs       = blockBase + (size_t)nblk * PB;        // E
    unsigned short* h116 = (unsigned short*)regD;

    unsigned short* msg0  = (unsigned short*)d_out;
    unsigned char*  feat8 = (unsigned char*)d_out + (size_t)N * D * 2;
    unsigned char*  h18   = (unsigned char*)d_out + (size_t)N * D * 3;
    unsigned short* msg1  = feat16;
    (void)ws_size;

    const int gemm_blocks = (N + 127) / 128;
    const int gather_blocks = (N + 15) / 16;

    // --- zero bucketCnt, then fused prep + coarse count ---
    hipMemsetAsync(bucketCnt, 0, 512 * 4, stream);
    prep_count_kernel<<<PREP_BLKS + nblk, 256, 0, stream>>>(
        feat, feat16, feat8, Ws0, Wn0, Ws1, Wn1, wt0, wt1,
        edst, bucketCnt, blockBase, E);

    // --- partitioned CSR build ---
    part_scan_kernel<<<1, 512, 0, stream>>>(bucketCnt, bucketStart, E);
    part_scatter_kernel<<<nblk, 256, 0, stream>>>(esrc, edst, bucketStart, blockBase, pairs, E);
    part_fine_kernel<<<PB, 256, 0, stream>>>(pairs, bucketStart, row_ptr, col, N, E);

    // --- Layer 0 ---
    gather8_kernel<<<gather_blocks, 256, 0, stream>>>(feat8, row_ptr, col, indeg, msg0, N);
    mfma32_kernel<<<gemm_blocks, 256, 0, stream>>>(
        feat16, msg0, wt0, b0, lng, lnb, h116, h18, nullptr, N, 1);

    // --- Layer 1 ---
    gather8_kernel<<<gather_blocks, 256, 0, stream>>>(h18, row_ptr, col, indeg, msg1, N);
    mfma32_kernel<<<gemm_blocks, 256, 0, stream>>>(
        h116, msg1, wt1, b1, nullptr, nullptr, nullptr, nullptr, out, N, 0);
}